// Round 9
// baseline (740.614 us; speedup 1.0000x reference)
//
#include <hip/hip_runtime.h>
#include <cstdint>

#define B_ 256
#define T_ 512
#define D_ 128
#define U_ 128

typedef _Float16 h2_t __attribute__((ext_vector_type(2)));
typedef _Float16 f16x4 __attribute__((ext_vector_type(4)));
typedef _Float16 f16x8 __attribute__((ext_vector_type(8)));
typedef float f32x4 __attribute__((ext_vector_type(4)));

static __device__ __forceinline__ uint32_t pack2(float a, float b) {
  h2_t h;
  h.x = (_Float16)a;
  h.y = (_Float16)b;
  return __builtin_bit_cast(uint32_t, h);
}
static __device__ __forceinline__ h2_t as_h2(uint32_t u) {
  return __builtin_bit_cast(h2_t, u);
}
static __device__ __forceinline__ float dot2acc(uint32_t a, uint32_t w, float acc) {
#if __has_builtin(__builtin_amdgcn_fdot2)
  return __builtin_amdgcn_fdot2(as_h2(a), as_h2(w), acc, false);
#else
  h2_t ha = as_h2(a), hw = as_h2(w);
  return acc + (float)ha.x * (float)hw.x + (float)ha.y * (float)hw.y;
#endif
}

// ---- raw transcendentals (no div-fixup sequences) --------------------------
static __device__ __forceinline__ float fexp2(float x) {
#if __has_builtin(__builtin_amdgcn_exp2f)
  return __builtin_amdgcn_exp2f(x);
#else
  return __exp2f(x);
#endif
}
static __device__ __forceinline__ float frcp(float x) {
#if __has_builtin(__builtin_amdgcn_rcpf)
  return __builtin_amdgcn_rcpf(x);
#else
  return __frcp_rn(x);
#endif
}
#define LOG2E_ 1.44269504f
static __device__ __forceinline__ float sigm(float v) {
  return frcp(1.0f + fexp2(-LOG2E_ * v));
}
static __device__ __forceinline__ float tanh_(float v) {
  float r = frcp(1.0f + fexp2(-2.0f * LOG2E_ * v));
  return __builtin_fmaf(2.0f, r, -1.0f);
}
// branch-free 4-way select by lane-quadrant (uniform within 16-lane group)
static __device__ __forceinline__ float sel4(float a, float b, float c, float d, int lq) {
  float x = (lq & 1) ? b : a;
  float y = (lq & 1) ? d : c;
  return (lq & 2) ? y : x;
}

// ---------------- kernel 0: transpose W to f16 [col][k] ---------------------
__global__ __launch_bounds__(256) void wt_kernel(const float* __restrict__ W,
                                                 _Float16* __restrict__ Wtx,
                                                 _Float16* __restrict__ Wth) {
  int id = blockIdx.x * 256 + threadIdx.x;  // 131072 = 512 cols x 256 k
  int col = id >> 8, k = id & 255;
  _Float16 v = (_Float16)W[(size_t)k * 512 + col];
  if (k < 128) Wtx[col * 128 + k] = v;
  else Wth[col * 128 + (k - 128)] = v;
}

// ---------------- kernel A: gx2 = x @ Wx + bias' (f16, gate-interleaved) ----
__global__ __launch_bounds__(256, 2) void gx_kernel(const float* __restrict__ x,
                                                    const _Float16* __restrict__ Wt,
                                                    const float* __restrict__ bias,
                                                    _Float16* __restrict__ gx) {
  __shared__ __align__(16) _Float16 As[64 * 136];
  const int tid = threadIdx.x;
  const int w = tid >> 6, l = tid & 63;
  const size_t rowBase = (size_t)blockIdx.x * 64;

  const float4* xs = reinterpret_cast<const float4*>(x + rowBase * 128);
#pragma unroll
  for (int n = 0; n < 8; ++n) {
    int idx4 = tid + 256 * n;
    float4 v = xs[idx4];
    int f = idx4 * 4;
    int r = f >> 7, cc = f & 127;
    f16x4 p;
    p.x = (_Float16)v.x; p.y = (_Float16)v.y;
    p.z = (_Float16)v.z; p.w = (_Float16)v.w;
    *reinterpret_cast<f16x4*>(&As[r * 136 + cc]) = p;
  }
  __syncthreads();

  f16x8 af[4][4];
#pragma unroll
  for (int rt = 0; rt < 4; ++rt)
#pragma unroll
    for (int kk = 0; kk < 4; ++kk)
      af[rt][kk] = *reinterpret_cast<const f16x8*>(
          &As[(16 * rt + (l & 15)) * 136 + 32 * kk + 8 * (l >> 4)]);

  const int colBase = 128 * w;
#pragma unroll 1
  for (int ct = 0; ct < 8; ++ct) {
    const int col = colBase + 16 * ct + (l & 15);
    const float bb = bias[col] + ((col >= 256 && col < 384) ? 1.0f : 0.0f);
    f32x4 acc[4];
#pragma unroll
    for (int rt = 0; rt < 4; ++rt) acc[rt] = (f32x4){0.f, 0.f, 0.f, 0.f};
    const _Float16* wtc = Wt + (size_t)col * 128 + 8 * (l >> 4);
#pragma unroll
    for (int kk = 0; kk < 4; ++kk) {
      f16x8 bf = *reinterpret_cast<const f16x8*>(wtc + 32 * kk);
#pragma unroll
      for (int rt = 0; rt < 4; ++rt)
        acc[rt] = __builtin_amdgcn_mfma_f32_16x16x32_f16(af[rt][kk], bf, acc[rt], 0, 0, 0);
    }
    const int u = col & 127, g = col >> 7;
#pragma unroll
    for (int rt = 0; rt < 4; ++rt) {
      size_t row = rowBase + 16 * rt + 4 * (l >> 4);
#pragma unroll
      for (int j = 0; j < 4; ++j)
        gx[(row + j) * 512 + u * 4 + g] = (_Float16)(acc[rt][j] + bb);
    }
  }
}

// ---------------- kernel B: 4-batch interleaved MFMA recurrence -------------
// Grid 64, 512 thr. Block owns batches b0..b0+3. Per barrier period all 4
// batches advance one step: their chains overlap, barrier cost /4, and the
// epilogue runs batch=lq per lane-quadrant (every lane does ONE update).
__global__ __launch_bounds__(512, 1) void rec_kernel(
    const _Float16* __restrict__ Wth,  // [512 cols][128 k] f16
    const uint16_t* __restrict__ gx2,  // [B*T][128][4] f16 bits
    float* __restrict__ out) {
  // h per batch: 128 f16, stride 144 (q*72 dwords -> +8q banks: disjoint sets)
  __shared__ __align__(16) _Float16 hbuf[2][4 * 144];
  const int tid = threadIdx.x;
  const int w = tid >> 6, l = tid & 63;
  const int lq = l >> 4;
  const int u = 16 * w + (l & 15);
  const int b = blockIdx.x * 4 + lq;  // this lane's batch

  // B fragments (per wave, shared by all batches): bw[g][kk]
  f16x8 bw[4][4];
#pragma unroll
  for (int g = 0; g < 4; ++g) {
    const _Float16* wc = Wth + (size_t)(128 * g + u) * 128 + 8 * lq;
#pragma unroll
    for (int kk = 0; kk < 4; ++kk)
      bw[g][kk] = *reinterpret_cast<const f16x8*>(wc + 32 * kk);
  }
#pragma unroll
  for (int g = 0; g < 4; ++g)
#pragma unroll
    for (int kk = 0; kk < 4; ++kk)
      asm volatile("" : "+a"(bw[g][kk]));  // pin in AGPRs

  const uint16_t* gxb = gx2 + (size_t)b * T_ * 512 + 4 * u;
  float* ob = out + (size_t)b * T_ * U_ + u;

  // zero both h buffers: 2*4*144 f16 = 576 dwords
  for (int i = tid; i < 576; i += 512)
    reinterpret_cast<uint32_t*>(&hbuf[0][0])[i] = 0u;

  f32x4 Z = {0.f, 0.f, 0.f, 0.f};
  asm volatile("" : "+v"(Z));
  float cst = 0.0f;

#define GXLD(idx) \
  (*reinterpret_cast<const f16x4*>(gxb + (size_t)((idx) < T_ ? (idx) : (T_ - 1)) * 512))

  f16x4 gA = GXLD(0), gB = GXLD(1);
  __syncthreads();

#define MFMA_INIT(d, a, bfr)                    \
  asm("v_mfma_f32_16x16x32_f16 %0, %1, %2, %3"  \
      : "=v"(d) : "v"(a), "a"(bfr), "v"(Z))
#define MFMA_ACC(d, a, bfr)                     \
  asm("v_mfma_f32_16x16x32_f16 %0, %1, %2, %0"  \
      : "+v"(d) : "v"(a), "a"(bfr))

#define LDS_BARRIER()                                                  \
  do {                                                                 \
    asm volatile("s_waitcnt lgkmcnt(0)\n\ts_barrier" ::: "memory");    \
    __builtin_amdgcn_sched_barrier(0);                                 \
  } while (0)

// 16 MFMAs for one batch: A-frags a0..a3, acc c0..c3 (kk 0,1) + d0..d3 (kk 2,3)
#define MF16(a0_, a1_, a2_, a3_, c0_, c1_, c2_, c3_, d0_, d1_, d2_, d3_) \
  MFMA_INIT(c0_, a0_, bw[0][0]); MFMA_INIT(c1_, a0_, bw[1][0]);          \
  MFMA_INIT(c2_, a0_, bw[2][0]); MFMA_INIT(c3_, a0_, bw[3][0]);          \
  MFMA_INIT(d0_, a2_, bw[0][2]); MFMA_INIT(d1_, a2_, bw[1][2]);          \
  MFMA_INIT(d2_, a2_, bw[2][2]); MFMA_INIT(d3_, a2_, bw[3][2]);          \
  MFMA_ACC(c0_, a1_, bw[0][1]);  MFMA_ACC(c1_, a1_, bw[1][1]);           \
  MFMA_ACC(c2_, a1_, bw[2][1]);  MFMA_ACC(c3_, a1_, bw[3][1]);           \
  MFMA_ACC(d0_, a3_, bw[0][3]);  MFMA_ACC(d1_, a3_, bw[1][3]);           \
  MFMA_ACC(d2_, a3_, bw[2][3]);  MFMA_ACC(d3_, a3_, bw[3][3]);

// extract the 4 gate scalars (row-replicated -> element [0]) with hazard guard
#define EXTRACT(gi_, gj_, gf_, go_, c0_, c1_, c2_, c3_, d0_, d1_, d2_, d3_)    \
  asm volatile("s_nop 7\n\ts_nop 7"                                            \
               : "+v"(c0_), "+v"(c1_), "+v"(c2_), "+v"(c3_),                   \
                 "+v"(d0_), "+v"(d1_), "+v"(d2_), "+v"(d3_));                  \
  gi_ = c0_[0] + d0_[0]; gj_ = c1_[0] + d1_[0];                                \
  gf_ = c2_[0] + d2_[0]; go_ = c3_[0] + d3_[0];

#define LDH(hp, q, kk) \
  (*reinterpret_cast<const f16x8*>((hp) + (q) * 144 + 32 * (kk) + 8 * lq))

#define PERIOD(tt, p, gv)                                                      \
  {                                                                            \
    const _Float16* hp = &hbuf[p][0];                                          \
    f16x8 A00 = LDH(hp, 0, 0), A01 = LDH(hp, 0, 1),                            \
          A02 = LDH(hp, 0, 2), A03 = LDH(hp, 0, 3);                            \
    f16x8 A10 = LDH(hp, 1, 0), A11 = LDH(hp, 1, 1),                            \
          A12 = LDH(hp, 1, 2), A13 = LDH(hp, 1, 3);                            \
    f16x8 A20 = LDH(hp, 2, 0), A21 = LDH(hp, 2, 1),                            \
          A22 = LDH(hp, 2, 2), A23 = LDH(hp, 2, 3);                            \
    f16x8 A30 = LDH(hp, 3, 0), A31 = LDH(hp, 3, 1),                            \
          A32 = LDH(hp, 3, 2), A33 = LDH(hp, 3, 3);                            \
    f32x4 X0, X1, X2, X3, X4, X5, X6, X7;                                      \
    f32x4 Y0, Y1, Y2, Y3, Y4, Y5, Y6, Y7;                                      \
    float G0i, G0j, G0f, G0o, G1i, G1j, G1f, G1o;                              \
    float G2i, G2j, G2f, G2o, G3i, G3j, G3f, G3o;                              \
    MF16(A00, A01, A02, A03, X0, X1, X2, X3, X4, X5, X6, X7)                   \
    MF16(A10, A11, A12, A13, Y0, Y1, Y2, Y3, Y4, Y5, Y6, Y7)                   \
    EXTRACT(G0i, G0j, G0f, G0o, X0, X1, X2, X3, X4, X5, X6, X7)                \
    MF16(A20, A21, A22, A23, X0, X1, X2, X3, X4, X5, X6, X7)                   \
    EXTRACT(G1i, G1j, G1f, G1o, Y0, Y1, Y2, Y3, Y4, Y5, Y6, Y7)                \
    MF16(A30, A31, A32, A33, Y0, Y1, Y2, Y3, Y4, Y5, Y6, Y7)                   \
    EXTRACT(G2i, G2j, G2f, G2o, X0, X1, X2, X3, X4, X5, X6, X7)                \
    EXTRACT(G3i, G3j, G3f, G3o, Y0, Y1, Y2, Y3, Y4, Y5, Y6, Y7)                \
    float gi = sel4(G0i, G1i, G2i, G3i, lq) + (float)(gv).x;                   \
    float gj = sel4(G0j, G1j, G2j, G3j, lq) + (float)(gv).y;                   \
    float gf = sel4(G0f, G1f, G2f, G3f, lq) + (float)(gv).z;                   \
    float go = sel4(G0o, G1o, G2o, G3o, lq) + (float)(gv).w;                   \
    cst = __builtin_fmaf(cst, sigm(gf), sigm(gi) * tanh_(gj));                 \
    const float hh = tanh_(cst) * sigm(go);                                    \
    hbuf[(p) ^ 1][lq * 144 + u] = (_Float16)hh;                                \
    ob[(size_t)(tt) * U_] = hh;                                                \
    LDS_BARRIER();                                                             \
  }

#pragma unroll 1
  for (int t = 0; t < T_; t += 2) {
    PERIOD(t + 0, 0, gA)
    gA = GXLD(t + 2);
    PERIOD(t + 1, 1, gB)
    gB = GXLD(t + 3);
  }
#undef PERIOD
#undef LDH
#undef EXTRACT
#undef MF16
#undef LDS_BARRIER
#undef MFMA_INIT
#undef MFMA_ACC
#undef GXLD
}

// ---------------- round-1 fallback (ws too small) ---------------------------
__global__ __launch_bounds__(512, 2) void lstm_fused_kernel(
    const float* __restrict__ x, const float* __restrict__ W,
    const float* __restrict__ bias, float* __restrict__ out) {
  __shared__ __align__(16) uint32_t a_lds[2][128];
  __shared__ float g_lds[512];
  const int tid = threadIdx.x;
  const int b = blockIdx.x;
  uint32_t wreg[128];
#pragma unroll
  for (int q4 = 0; q4 < 32; ++q4) {
    float f[8];
#pragma unroll
    for (int r = 0; r < 8; ++r) f[r] = W[(q4 * 8 + r) * 512 + tid];
#pragma unroll
    for (int rr = 0; rr < 4; ++rr)
      wreg[q4 * 4 + rr] = pack2(f[2 * rr], f[2 * rr + 1]);
  }
  const float bjv = bias[tid];
  const float* xb = x + (size_t)b * (T_ * D_);
  float* ob = out + (size_t)b * (T_ * U_);
  if (tid < 32) {
    float4 x4 = reinterpret_cast<const float4*>(xb)[tid];
    reinterpret_cast<uint2*>(&a_lds[0][0])[tid] =
        make_uint2(pack2(x4.x, x4.y), pack2(x4.z, x4.w));
  }
  if (tid >= 64 && tid < 128) a_lds[0][tid] = 0u;
  __syncthreads();
  float c = 0.0f;
  int p = 0;
  for (int t = 0; t < T_; ++t) {
    float4 xp;
    const bool pf = (tid < 32) && (t + 1 < T_);
    if (pf) xp = reinterpret_cast<const float4*>(xb + (t + 1) * D_)[tid];
    const uint4* av = reinterpret_cast<const uint4*>(&a_lds[p][0]);
    float a0 = bjv, a1 = 0.0f, a2 = 0.0f, a3 = 0.0f;
#pragma unroll
    for (int q = 0; q < 32; ++q) {
      uint4 a4 = av[q];
      a0 = dot2acc(a4.x, wreg[4 * q + 0], a0);
      a1 = dot2acc(a4.y, wreg[4 * q + 1], a1);
      a2 = dot2acc(a4.z, wreg[4 * q + 2], a2);
      a3 = dot2acc(a4.w, wreg[4 * q + 3], a3);
    }
    g_lds[tid] = (a0 + a1) + (a2 + a3);
    __syncthreads();
    if (tid < 128) {
      const float gi = g_lds[tid];
      const float gj = g_lds[128 + tid];
      const float gf = g_lds[256 + tid];
      const float go = g_lds[384 + tid];
      c = c * sigm(gf + 1.0f) + sigm(gi) * tanh_(gj);
      const float h = tanh_(c) * sigm(go);
      ob[t * U_ + tid] = h;
      reinterpret_cast<_Float16*>(&a_lds[p ^ 1][64])[tid] = (_Float16)h;
    }
    if (pf) {
      reinterpret_cast<uint2*>(&a_lds[p ^ 1][0])[tid] =
          make_uint2(pack2(xp.x, xp.y), pack2(xp.z, xp.w));
    }
    __syncthreads();
    p ^= 1;
  }
}

extern "C" void kernel_launch(void* const* d_in, const int* in_sizes, int n_in,
                              void* d_out, int out_size, void* d_ws, size_t ws_size,
                              hipStream_t stream) {
  (void)in_sizes; (void)n_in; (void)out_size;
  const float* x = (const float*)d_in[0];
  const float* W = (const float*)d_in[1];
  const float* b = (const float*)d_in[2];
  float* out = (float*)d_out;

  const size_t WTX_BYTES = (size_t)512 * 128 * 2;
  const size_t WTH_BYTES = (size_t)512 * 128 * 2;
  const size_t GX_BYTES = (size_t)B_ * T_ * 512 * 2;
  if (ws_size >= WTX_BYTES + WTH_BYTES + GX_BYTES) {
    _Float16* wtx = (_Float16*)d_ws;
    _Float16* wth = (_Float16*)((char*)d_ws + WTX_BYTES);
    _Float16* gxp = (_Float16*)((char*)d_ws + WTX_BYTES + WTH_BYTES);
    wt_kernel<<<512, 256, 0, stream>>>(W, wtx, wth);
    gx_kernel<<<2048, 256, 0, stream>>>(x, wtx, b, gxp);
    rec_kernel<<<64, 512, 0, stream>>>(wth, (const uint16_t*)gxp, out);
  } else {
    lstm_fused_kernel<<<256, 512, 0, stream>>>(x, W, b, out);
  }
}

// Round 10
// 348.584 us; speedup vs baseline: 2.1246x; 2.1246x over previous
//
#include <hip/hip_runtime.h>
#include <cstdint>

#define B_ 256
#define T_ 512
#define D_ 128
#define U_ 128

typedef _Float16 h2_t __attribute__((ext_vector_type(2)));
typedef _Float16 f16x4 __attribute__((ext_vector_type(4)));
typedef _Float16 f16x8 __attribute__((ext_vector_type(8)));
typedef float f32x4 __attribute__((ext_vector_type(4)));

static __device__ __forceinline__ uint32_t pack2(float a, float b) {
  h2_t h;
  h.x = (_Float16)a;
  h.y = (_Float16)b;
  return __builtin_bit_cast(uint32_t, h);
}
static __device__ __forceinline__ h2_t as_h2(uint32_t u) {
  return __builtin_bit_cast(h2_t, u);
}
static __device__ __forceinline__ float dot2acc(uint32_t a, uint32_t w, float acc) {
#if __has_builtin(__builtin_amdgcn_fdot2)
  return __builtin_amdgcn_fdot2(as_h2(a), as_h2(w), acc, false);
#else
  h2_t ha = as_h2(a), hw = as_h2(w);
  return acc + (float)ha.x * (float)hw.x + (float)ha.y * (float)hw.y;
#endif
}

// ---- raw transcendentals (no div-fixup sequences) --------------------------
static __device__ __forceinline__ float fexp2(float x) {
#if __has_builtin(__builtin_amdgcn_exp2f)
  return __builtin_amdgcn_exp2f(x);
#else
  return __exp2f(x);
#endif
}
static __device__ __forceinline__ float frcp(float x) {
#if __has_builtin(__builtin_amdgcn_rcpf)
  return __builtin_amdgcn_rcpf(x);
#else
  return __frcp_rn(x);
#endif
}
#define LOG2E_ 1.44269504f
static __device__ __forceinline__ float sigm(float v) {
  return frcp(1.0f + fexp2(-LOG2E_ * v));
}
static __device__ __forceinline__ float tanh_(float v) {
  float r = frcp(1.0f + fexp2(-2.0f * LOG2E_ * v));
  return __builtin_fmaf(2.0f, r, -1.0f);
}

// ---------------- kernel 0: transpose W to f16 [col][k] ---------------------
__global__ __launch_bounds__(256) void wt_kernel(const float* __restrict__ W,
                                                 _Float16* __restrict__ Wtx,
                                                 _Float16* __restrict__ Wth) {
  int id = blockIdx.x * 256 + threadIdx.x;  // 131072 = 512 cols x 256 k
  int col = id >> 8, k = id & 255;
  _Float16 v = (_Float16)W[(size_t)k * 512 + col];
  if (k < 128) Wtx[col * 128 + k] = v;
  else Wth[col * 128 + (k - 128)] = v;
}

// ---------------- kernel A: gx2 = x @ Wx + bias' (f16, gate-interleaved) ----
__global__ __launch_bounds__(256, 2) void gx_kernel(const float* __restrict__ x,
                                                    const _Float16* __restrict__ Wt,
                                                    const float* __restrict__ bias,
                                                    _Float16* __restrict__ gx) {
  __shared__ __align__(16) _Float16 As[64 * 136];
  const int tid = threadIdx.x;
  const int w = tid >> 6, l = tid & 63;
  const size_t rowBase = (size_t)blockIdx.x * 64;

  const float4* xs = reinterpret_cast<const float4*>(x + rowBase * 128);
#pragma unroll
  for (int n = 0; n < 8; ++n) {
    int idx4 = tid + 256 * n;
    float4 v = xs[idx4];
    int f = idx4 * 4;
    int r = f >> 7, cc = f & 127;
    f16x4 p;
    p.x = (_Float16)v.x; p.y = (_Float16)v.y;
    p.z = (_Float16)v.z; p.w = (_Float16)v.w;
    *reinterpret_cast<f16x4*>(&As[r * 136 + cc]) = p;
  }
  __syncthreads();

  f16x8 af[4][4];
#pragma unroll
  for (int rt = 0; rt < 4; ++rt)
#pragma unroll
    for (int kk = 0; kk < 4; ++kk)
      af[rt][kk] = *reinterpret_cast<const f16x8*>(
          &As[(16 * rt + (l & 15)) * 136 + 32 * kk + 8 * (l >> 4)]);

  const int colBase = 128 * w;
#pragma unroll 1
  for (int ct = 0; ct < 8; ++ct) {
    const int col = colBase + 16 * ct + (l & 15);
    const float bb = bias[col] + ((col >= 256 && col < 384) ? 1.0f : 0.0f);
    f32x4 acc[4];
#pragma unroll
    for (int rt = 0; rt < 4; ++rt) acc[rt] = (f32x4){0.f, 0.f, 0.f, 0.f};
    const _Float16* wtc = Wt + (size_t)col * 128 + 8 * (l >> 4);
#pragma unroll
    for (int kk = 0; kk < 4; ++kk) {
      f16x8 bf = *reinterpret_cast<const f16x8*>(wtc + 32 * kk);
#pragma unroll
      for (int rt = 0; rt < 4; ++rt)
        acc[rt] = __builtin_amdgcn_mfma_f32_16x16x32_f16(af[rt][kk], bf, acc[rt], 0, 0, 0);
    }
    const int u = col & 127, g = col >> 7;
#pragma unroll
    for (int rt = 0; rt < 4; ++rt) {
      size_t row = rowBase + 16 * rt + 4 * (l >> 4);
#pragma unroll
      for (int j = 0; j < 4; ++j)
        gx[(row + j) * 512 + u * 4 + g] = (_Float16)(acc[rt][j] + bb);
    }
  }
}

// ---------------- kernel B: 4-wave lean MFMA recurrence ---------------------
// 256 thr = 4 waves, grid 256 (1 batch/CU, 1 wave/SIMD). Wave w owns units
// [32w, 32w+32): 8 col-tiles {8g + 2w + s} x 4 k-tiles = 32 MFMA/wave.
// Every lane holds gates of units u_s = 32w + 16s + (l&15) (s=0,1) in
// acc[g*2+s][0] (rows broadcast-identical). 2 in-lane updates per lane.
__global__ __launch_bounds__(256, 1) void rec_kernel(
    const _Float16* __restrict__ Wth,  // [512 cols][128 k] f16
    const uint16_t* __restrict__ gx2,  // [B*T][128][4] f16 bits
    float* __restrict__ out) {
  __shared__ __align__(16) _Float16 hbuf[2][128];  // h dbuf, 512 B
  const int tid = threadIdx.x;
  const int b = blockIdx.x;
  const int w = tid >> 6, l = tid & 63;
  const int lq = l >> 4;
  const int cI = l & 15;
  const bool wr = (lq == 0);

  // weight frags: bw[g*2+s][kt] = Wth[col = 128g+32w+16s+cI][32kt+8lq ..+8]
  f16x8 bw[8][4];
#pragma unroll
  for (int g = 0; g < 4; ++g)
#pragma unroll
    for (int s = 0; s < 2; ++s) {
      const _Float16* wc =
          Wth + (size_t)(128 * g + 32 * w + 16 * s + cI) * 128 + 8 * lq;
#pragma unroll
      for (int kt = 0; kt < 4; ++kt)
        bw[g * 2 + s][kt] = *reinterpret_cast<const f16x8*>(wc + 32 * kt);
    }
#pragma unroll
  for (int i = 0; i < 8; ++i)
#pragma unroll
    for (int kt = 0; kt < 4; ++kt)
      asm volatile("" : "+a"(bw[i][kt]));  // pin weights in AGPRs

  const int u0 = 32 * w + cI;
  const uint16_t* gxb = gx2 + (size_t)b * T_ * 512 + 4 * u0;
  float* ob = out + (size_t)b * T_ * U_ + u0;

  if (tid < 128) reinterpret_cast<uint32_t*>(&hbuf[0][0])[tid] = 0u;

  f32x4 Z = {0.f, 0.f, 0.f, 0.f};
  asm volatile("" : "+v"(Z));
  float cst0 = 0.0f, cst1 = 0.0f;

// per step: s0 gates = f16x4 at [t*512], s1 gates at [t*512 + 64]
#define GXA(idx) (*reinterpret_cast<const f16x4*>( \
    gxb + (size_t)((idx) < T_ ? (idx) : (T_ - 1)) * 512))
#define GXB(idx) (*reinterpret_cast<const f16x4*>( \
    gxb + (size_t)((idx) < T_ ? (idx) : (T_ - 1)) * 512 + 64))

  f16x4 g0a = GXA(0), g0b = GXB(0), g1a = GXA(1), g1b = GXB(1);
  f16x4 g2a = GXA(2), g2b = GXB(2), g3a = GXA(3), g3b = GXB(3);
  __syncthreads();

#define MFMA_INIT(d, a, bfr)                    \
  asm("v_mfma_f32_16x16x32_f16 %0, %1, %2, %3"  \
      : "=v"(d) : "v"(a), "a"(bfr), "v"(Z))
#define MFMA_ACC(d, a, bfr)                     \
  asm("v_mfma_f32_16x16x32_f16 %0, %1, %2, %0"  \
      : "+v"(d) : "v"(a), "a"(bfr))

#define LDS_BARRIER()                                                  \
  do {                                                                 \
    asm volatile("s_waitcnt lgkmcnt(0)\n\ts_barrier" ::: "memory");    \
    __builtin_amdgcn_sched_barrier(0);                                 \
  } while (0)

#define STEP(tt, p, gva, gvb)                                                  \
  {                                                                            \
    const _Float16* hb = &hbuf[p][0];                                          \
    f16x8 a0 = *reinterpret_cast<const f16x8*>(hb + 8 * lq);                   \
    f16x8 a1 = *reinterpret_cast<const f16x8*>(hb + 32 + 8 * lq);              \
    f16x8 a2 = *reinterpret_cast<const f16x8*>(hb + 64 + 8 * lq);              \
    f16x8 a3 = *reinterpret_cast<const f16x8*>(hb + 96 + 8 * lq);              \
    f32x4 q0, q1, q2, q3, q4, q5, q6, q7;                                      \
    MFMA_INIT(q0, a0, bw[0][0]); MFMA_INIT(q1, a0, bw[1][0]);                  \
    MFMA_INIT(q2, a0, bw[2][0]); MFMA_INIT(q3, a0, bw[3][0]);                  \
    MFMA_INIT(q4, a0, bw[4][0]); MFMA_INIT(q5, a0, bw[5][0]);                  \
    MFMA_INIT(q6, a0, bw[6][0]); MFMA_INIT(q7, a0, bw[7][0]);                  \
    MFMA_ACC(q0, a1, bw[0][1]);  MFMA_ACC(q1, a1, bw[1][1]);                   \
    MFMA_ACC(q2, a1, bw[2][1]);  MFMA_ACC(q3, a1, bw[3][1]);                   \
    MFMA_ACC(q4, a1, bw[4][1]);  MFMA_ACC(q5, a1, bw[5][1]);                   \
    MFMA_ACC(q6, a1, bw[6][1]);  MFMA_ACC(q7, a1, bw[7][1]);                   \
    MFMA_ACC(q0, a2, bw[0][2]);  MFMA_ACC(q1, a2, bw[1][2]);                   \
    MFMA_ACC(q2, a2, bw[2][2]);  MFMA_ACC(q3, a2, bw[3][2]);                   \
    MFMA_ACC(q4, a2, bw[4][2]);  MFMA_ACC(q5, a2, bw[5][2]);                   \
    MFMA_ACC(q6, a2, bw[6][2]);  MFMA_ACC(q7, a2, bw[7][2]);                   \
    MFMA_ACC(q0, a3, bw[0][3]);  MFMA_ACC(q1, a3, bw[1][3]);                   \
    MFMA_ACC(q2, a3, bw[2][3]);  MFMA_ACC(q3, a3, bw[3][3]);                   \
    MFMA_ACC(q4, a3, bw[4][3]);  MFMA_ACC(q5, a3, bw[5][3]);                   \
    MFMA_ACC(q6, a3, bw[6][3]);  MFMA_ACC(q7, a3, bw[7][3]);                   \
    asm volatile("s_nop 7\n\ts_nop 7"                                          \
                 : "+v"(q0), "+v"(q1), "+v"(q2), "+v"(q3),                     \
                   "+v"(q4), "+v"(q5), "+v"(q6), "+v"(q7));                    \
    /* i = g*2+s: q0/q2/q4/q6 = gates i,j,f,o of s=0; q1/q3/q5/q7 of s=1 */    \
    const float gi0 = q0[0] + (float)(gva).x;                                  \
    const float gj0 = q2[0] + (float)(gva).y;                                  \
    const float gf0 = q4[0] + (float)(gva).z;                                  \
    const float go0 = q6[0] + (float)(gva).w;                                  \
    const float gi1 = q1[0] + (float)(gvb).x;                                  \
    const float gj1 = q3[0] + (float)(gvb).y;                                  \
    const float gf1 = q5[0] + (float)(gvb).z;                                  \
    const float go1 = q7[0] + (float)(gvb).w;                                  \
    cst0 = __builtin_fmaf(cst0, sigm(gf0), sigm(gi0) * tanh_(gj0));            \
    cst1 = __builtin_fmaf(cst1, sigm(gf1), sigm(gi1) * tanh_(gj1));            \
    const float h0 = tanh_(cst0) * sigm(go0);                                  \
    const float h1 = tanh_(cst1) * sigm(go1);                                  \
    if (wr) {                                                                  \
      hbuf[(p) ^ 1][u0] = (_Float16)h0;                                        \
      hbuf[(p) ^ 1][u0 + 16] = (_Float16)h1;                                   \
      ob[(size_t)(tt) * U_] = h0;                                              \
      ob[(size_t)(tt) * U_ + 16] = h1;                                         \
    }                                                                          \
    LDS_BARRIER();                                                             \
  }

#pragma unroll 1
  for (int t = 0; t < T_; t += 4) {
    STEP(t + 0, 0, g0a, g0b)
    g0a = GXA(t + 4); g0b = GXB(t + 4);
    STEP(t + 1, 1, g1a, g1b)
    g1a = GXA(t + 5); g1b = GXB(t + 5);
    STEP(t + 2, 0, g2a, g2b)
    g2a = GXA(t + 6); g2b = GXB(t + 6);
    STEP(t + 3, 1, g3a, g3b)
    g3a = GXA(t + 7); g3b = GXB(t + 7);
  }
#undef STEP
#undef LDS_BARRIER
#undef MFMA_INIT
#undef MFMA_ACC
#undef GXA
#undef GXB
}

// ---------------- round-1 fallback (ws too small) ---------------------------
__global__ __launch_bounds__(512, 2) void lstm_fused_kernel(
    const float* __restrict__ x, const float* __restrict__ W,
    const float* __restrict__ bias, float* __restrict__ out) {
  __shared__ __align__(16) uint32_t a_lds[2][128];
  __shared__ float g_lds[512];
  const int tid = threadIdx.x;
  const int b = blockIdx.x;
  uint32_t wreg[128];
#pragma unroll
  for (int q4 = 0; q4 < 32; ++q4) {
    float f[8];
#pragma unroll
    for (int r = 0; r < 8; ++r) f[r] = W[(q4 * 8 + r) * 512 + tid];
#pragma unroll
    for (int rr = 0; rr < 4; ++rr)
      wreg[q4 * 4 + rr] = pack2(f[2 * rr], f[2 * rr + 1]);
  }
  const float bjv = bias[tid];
  const float* xb = x + (size_t)b * (T_ * D_);
  float* ob = out + (size_t)b * (T_ * U_);
  if (tid < 32) {
    float4 x4 = reinterpret_cast<const float4*>(xb)[tid];
    reinterpret_cast<uint2*>(&a_lds[0][0])[tid] =
        make_uint2(pack2(x4.x, x4.y), pack2(x4.z, x4.w));
  }
  if (tid >= 64 && tid < 128) a_lds[0][tid] = 0u;
  __syncthreads();
  float c = 0.0f;
  int p = 0;
  for (int t = 0; t < T_; ++t) {
    float4 xp;
    const bool pf = (tid < 32) && (t + 1 < T_);
    if (pf) xp = reinterpret_cast<const float4*>(xb + (t + 1) * D_)[tid];
    const uint4* av = reinterpret_cast<const uint4*>(&a_lds[p][0]);
    float a0 = bjv, a1 = 0.0f, a2 = 0.0f, a3 = 0.0f;
#pragma unroll
    for (int q = 0; q < 32; ++q) {
      uint4 a4 = av[q];
      a0 = dot2acc(a4.x, wreg[4 * q + 0], a0);
      a1 = dot2acc(a4.y, wreg[4 * q + 1], a1);
      a2 = dot2acc(a4.z, wreg[4 * q + 2], a2);
      a3 = dot2acc(a4.w, wreg[4 * q + 3], a3);
    }
    g_lds[tid] = (a0 + a1) + (a2 + a3);
    __syncthreads();
    if (tid < 128) {
      const float gi = g_lds[tid];
      const float gj = g_lds[128 + tid];
      const float gf = g_lds[256 + tid];
      const float go = g_lds[384 + tid];
      c = c * sigm(gf + 1.0f) + sigm(gi) * tanh_(gj);
      const float h = tanh_(c) * sigm(go);
      ob[t * U_ + tid] = h;
      reinterpret_cast<_Float16*>(&a_lds[p ^ 1][64])[tid] = (_Float16)h;
    }
    if (pf) {
      reinterpret_cast<uint2*>(&a_lds[p ^ 1][0])[tid] =
          make_uint2(pack2(xp.x, xp.y), pack2(xp.z, xp.w));
    }
    __syncthreads();
    p ^= 1;
  }
}

extern "C" void kernel_launch(void* const* d_in, const int* in_sizes, int n_in,
                              void* d_out, int out_size, void* d_ws, size_t ws_size,
                              hipStream_t stream) {
  (void)in_sizes; (void)n_in; (void)out_size;
  const float* x = (const float*)d_in[0];
  const float* W = (const float*)d_in[1];
  const float* b = (const float*)d_in[2];
  float* out = (float*)d_out;

  const size_t WTX_BYTES = (size_t)512 * 128 * 2;
  const size_t WTH_BYTES = (size_t)512 * 128 * 2;
  const size_t GX_BYTES = (size_t)B_ * T_ * 512 * 2;
  if (ws_size >= WTX_BYTES + WTH_BYTES + GX_BYTES) {
    _Float16* wtx = (_Float16*)d_ws;
    _Float16* wth = (_Float16*)((char*)d_ws + WTX_BYTES);
    _Float16* gxp = (_Float16*)((char*)d_ws + WTX_BYTES + WTH_BYTES);
    wt_kernel<<<512, 256, 0, stream>>>(W, wtx, wth);
    gx_kernel<<<2048, 256, 0, stream>>>(x, wtx, b, gxp);
    rec_kernel<<<256, 256, 0, stream>>>(wth, (const uint16_t*)gxp, out);
  } else {
    lstm_fused_kernel<<<256, 512, 0, stream>>>(x, W, b, out);
  }
}

// Round 11
// 338.333 us; speedup vs baseline: 2.1890x; 1.0303x over previous
//
#include <hip/hip_runtime.h>
#include <cstdint>

#define B_ 256
#define T_ 512
#define D_ 128
#define U_ 128

typedef _Float16 h2_t __attribute__((ext_vector_type(2)));
typedef _Float16 f16x4 __attribute__((ext_vector_type(4)));
typedef _Float16 f16x8 __attribute__((ext_vector_type(8)));
typedef float f32x4 __attribute__((ext_vector_type(4)));
typedef int i32x4 __attribute__((ext_vector_type(4)));

static __device__ __forceinline__ uint32_t pack2(float a, float b) {
  h2_t h;
  h.x = (_Float16)a;
  h.y = (_Float16)b;
  return __builtin_bit_cast(uint32_t, h);
}
static __device__ __forceinline__ h2_t as_h2(uint32_t u) {
  return __builtin_bit_cast(h2_t, u);
}
static __device__ __forceinline__ float dot2acc(uint32_t a, uint32_t w, float acc) {
#if __has_builtin(__builtin_amdgcn_fdot2)
  return __builtin_amdgcn_fdot2(as_h2(a), as_h2(w), acc, false);
#else
  h2_t ha = as_h2(a), hw = as_h2(w);
  return acc + (float)ha.x * (float)hw.x + (float)ha.y * (float)hw.y;
#endif
}

// ---- raw transcendentals (no div-fixup sequences) --------------------------
static __device__ __forceinline__ float fexp2(float x) {
#if __has_builtin(__builtin_amdgcn_exp2f)
  return __builtin_amdgcn_exp2f(x);
#else
  return __exp2f(x);
#endif
}
static __device__ __forceinline__ float frcp(float x) {
#if __has_builtin(__builtin_amdgcn_rcpf)
  return __builtin_amdgcn_rcpf(x);
#else
  return __frcp_rn(x);
#endif
}
#define LOG2E_ 1.44269504f
static __device__ __forceinline__ float sigm(float v) {
  return frcp(1.0f + fexp2(-LOG2E_ * v));
}
static __device__ __forceinline__ float tanh_(float v) {
  float r = frcp(1.0f + fexp2(-2.0f * LOG2E_ * v));
  return __builtin_fmaf(2.0f, r, -1.0f);
}

// DPP row_ror:4 on a 4-dword vector (rotate within each 16-lane row).
// Used to fetch the neighbor quad's LDS read; +-4 both flip c0, so the
// rotate direction is irrelevant.
static __device__ __forceinline__ f16x8 dpp_ror4(f16x8 v) {
  i32x4 s = __builtin_bit_cast(i32x4, v), d;
#pragma unroll
  for (int i = 0; i < 4; ++i)
    d[i] = __builtin_amdgcn_mov_dpp(s[i], 0x124, 0xF, 0xF, true);
  return __builtin_bit_cast(f16x8, d);
}

// ---------------- kernel 0: transpose W to f16 [col][k] ---------------------
__global__ __launch_bounds__(256) void wt_kernel(const float* __restrict__ W,
                                                 _Float16* __restrict__ Wtx,
                                                 _Float16* __restrict__ Wth) {
  int id = blockIdx.x * 256 + threadIdx.x;  // 131072 = 512 cols x 256 k
  int col = id >> 8, k = id & 255;
  _Float16 v = (_Float16)W[(size_t)k * 512 + col];
  if (k < 128) Wtx[col * 128 + k] = v;
  else Wth[col * 128 + (k - 128)] = v;
}

// ---------------- kernel A: gx2 = x @ Wx + bias' (f16, gate-interleaved) ----
__global__ __launch_bounds__(256, 2) void gx_kernel(const float* __restrict__ x,
                                                    const _Float16* __restrict__ Wt,
                                                    const float* __restrict__ bias,
                                                    _Float16* __restrict__ gx) {
  __shared__ __align__(16) _Float16 As[64 * 136];
  const int tid = threadIdx.x;
  const int w = tid >> 6, l = tid & 63;
  const size_t rowBase = (size_t)blockIdx.x * 64;

  const float4* xs = reinterpret_cast<const float4*>(x + rowBase * 128);
#pragma unroll
  for (int n = 0; n < 8; ++n) {
    int idx4 = tid + 256 * n;
    float4 v = xs[idx4];
    int f = idx4 * 4;
    int r = f >> 7, cc = f & 127;
    f16x4 p;
    p.x = (_Float16)v.x; p.y = (_Float16)v.y;
    p.z = (_Float16)v.z; p.w = (_Float16)v.w;
    *reinterpret_cast<f16x4*>(&As[r * 136 + cc]) = p;
  }
  __syncthreads();

  f16x8 af[4][4];
#pragma unroll
  for (int rt = 0; rt < 4; ++rt)
#pragma unroll
    for (int kk = 0; kk < 4; ++kk)
      af[rt][kk] = *reinterpret_cast<const f16x8*>(
          &As[(16 * rt + (l & 15)) * 136 + 32 * kk + 8 * (l >> 4)]);

  const int colBase = 128 * w;
#pragma unroll 1
  for (int ct = 0; ct < 8; ++ct) {
    const int col = colBase + 16 * ct + (l & 15);
    const float bb = bias[col] + ((col >= 256 && col < 384) ? 1.0f : 0.0f);
    f32x4 acc[4];
#pragma unroll
    for (int rt = 0; rt < 4; ++rt) acc[rt] = (f32x4){0.f, 0.f, 0.f, 0.f};
    const _Float16* wtc = Wt + (size_t)col * 128 + 8 * (l >> 4);
#pragma unroll
    for (int kk = 0; kk < 4; ++kk) {
      f16x8 bf = *reinterpret_cast<const f16x8*>(wtc + 32 * kk);
#pragma unroll
      for (int rt = 0; rt < 4; ++rt)
        acc[rt] = __builtin_amdgcn_mfma_f32_16x16x32_f16(af[rt][kk], bf, acc[rt], 0, 0, 0);
    }
    const int u = col & 127, g = col >> 7;
#pragma unroll
    for (int rt = 0; rt < 4; ++rt) {
      size_t row = rowBase + 16 * rt + 4 * (l >> 4);
#pragma unroll
      for (int j = 0; j < 4; ++j)
        gx[(row + j) * 512 + u * 4 + g] = (_Float16)(acc[rt][j] + bb);
    }
  }
}

// ---------------- kernel B: MFMA recurrence, 2-read A-fragment scheme -------
// R8 base (8 waves, AGPR weights, LDS-only barrier) + LDS-pipe decongestion:
// each wave issues 2 ds_read_b128 (not 4); lane quads alternate kk-chunks
// (c0=(l>>2)&1), DPP row_ror:4 recovers the other chunk from the neighbor
// quad (same lq within a 16-lane row), cndmask materializes standard frags.
__global__ __launch_bounds__(512, 1) void rec_kernel(
    const _Float16* __restrict__ Wth,  // [512 cols][128 k] f16
    const uint16_t* __restrict__ gx2,  // [B*T][128][4] f16 bits
    float* __restrict__ out) {
  __shared__ __align__(16) _Float16 hbuf[2][128];  // h dbuf, 512 B
  const int tid = threadIdx.x;
  const int b = blockIdx.x;
  const int w = tid >> 6, l = tid & 63;
  const int lq = l >> 4;
  const int u = 16 * w + (l & 15);
  const bool wr = (lq == 0);
  const int c0 = (l >> 2) & 1;          // which kk-chunk this quad reads
  const bool c0z = (c0 == 0);
  const int hoffA = 8 * lq + 32 * c0;   // halfword offset: F[lq][c0]
  const int hoffB = hoffA + 64;         // F[lq][c0+2]

  // B fragments: bw[g][kk] = Wth[col=128g+u][k=32kk+8lq .. +8]
  f16x8 bw[4][4];
#pragma unroll
  for (int g = 0; g < 4; ++g) {
    const _Float16* wc = Wth + (size_t)(128 * g + u) * 128 + 8 * lq;
#pragma unroll
    for (int kk = 0; kk < 4; ++kk)
      bw[g][kk] = *reinterpret_cast<const f16x8*>(wc + 32 * kk);
  }
#pragma unroll
  for (int g = 0; g < 4; ++g)
#pragma unroll
    for (int kk = 0; kk < 4; ++kk)
      asm volatile("" : "+a"(bw[g][kk]));  // pin weights in AGPRs

  const uint16_t* gxb = gx2 + (size_t)b * T_ * 512 + 4 * u;
  float* ob = out + (size_t)b * T_ * U_ + u;

  if (tid < 128) reinterpret_cast<uint32_t*>(&hbuf[0][0])[tid] = 0u;

  f32x4 Z = {0.f, 0.f, 0.f, 0.f};
  asm volatile("" : "+v"(Z));
  float cst = 0.0f;

#define GXLD(idx) \
  (*reinterpret_cast<const f16x4*>(gxb + (size_t)((idx) < T_ ? (idx) : (T_ - 1)) * 512))

  f16x4 gp0 = GXLD(0), gp1 = GXLD(1), gp2 = GXLD(2), gp3 = GXLD(3);
  __syncthreads();

#define MFMA_INIT(d, a, bfr)                    \
  asm("v_mfma_f32_16x16x32_f16 %0, %1, %2, %3"  \
      : "=v"(d) : "v"(a), "a"(bfr), "v"(Z))
#define MFMA_ACC(d, a, bfr)                     \
  asm("v_mfma_f32_16x16x32_f16 %0, %1, %2, %0"  \
      : "+v"(d) : "v"(a), "a"(bfr))

#define LDS_BARRIER()                                                  \
  do {                                                                 \
    asm volatile("s_waitcnt lgkmcnt(0)\n\ts_barrier" ::: "memory");    \
    __builtin_amdgcn_sched_barrier(0);                                 \
  } while (0)

#define STEP(tt, p, gv)                                                        \
  {                                                                            \
    const _Float16* hb = &hbuf[p][0];                                          \
    f16x8 Ra = *reinterpret_cast<const f16x8*>(hb + hoffA);                    \
    f16x8 Rb = *reinterpret_cast<const f16x8*>(hb + hoffB);                    \
    f16x8 Ra4 = dpp_ror4(Ra);                                                  \
    f16x8 Rb4 = dpp_ror4(Rb);                                                  \
    f16x8 a0 = c0z ? Ra : Ra4;   /* F[lq][0] */                                \
    f16x8 a1 = c0z ? Ra4 : Ra;   /* F[lq][1] */                                \
    f16x8 a2 = c0z ? Rb : Rb4;   /* F[lq][2] */                                \
    f16x8 a3 = c0z ? Rb4 : Rb;   /* F[lq][3] */                                \
    f32x4 c0_, c1_, c2_, c3_, d0_, d1_, d2_, d3_;                              \
    MFMA_INIT(c0_, a0, bw[0][0]);                                              \
    MFMA_INIT(c1_, a0, bw[1][0]);                                              \
    MFMA_INIT(c2_, a0, bw[2][0]);                                              \
    MFMA_INIT(c3_, a0, bw[3][0]);                                              \
    MFMA_INIT(d0_, a2, bw[0][2]);                                              \
    MFMA_INIT(d1_, a2, bw[1][2]);                                              \
    MFMA_INIT(d2_, a2, bw[2][2]);                                              \
    MFMA_INIT(d3_, a2, bw[3][2]);                                              \
    MFMA_ACC(c0_, a1, bw[0][1]);                                               \
    MFMA_ACC(c1_, a1, bw[1][1]);                                               \
    MFMA_ACC(c2_, a1, bw[2][1]);                                               \
    MFMA_ACC(c3_, a1, bw[3][1]);                                               \
    MFMA_ACC(d0_, a3, bw[0][3]);                                               \
    MFMA_ACC(d1_, a3, bw[1][3]);                                               \
    MFMA_ACC(d2_, a3, bw[2][3]);                                               \
    MFMA_ACC(d3_, a3, bw[3][3]);                                               \
    asm volatile("s_nop 7\n\ts_nop 7"                                          \
                 : "+v"(c0_), "+v"(c1_), "+v"(c2_), "+v"(c3_),                 \
                   "+v"(d0_), "+v"(d1_), "+v"(d2_), "+v"(d3_));                \
    const float gi = (c0_[0] + d0_[0]) + (float)(gv).x;                        \
    const float gj = (c1_[0] + d1_[0]) + (float)(gv).y;                        \
    const float gf = (c2_[0] + d2_[0]) + (float)(gv).z;                        \
    const float go = (c3_[0] + d3_[0]) + (float)(gv).w;                        \
    cst = __builtin_fmaf(cst, sigm(gf), sigm(gi) * tanh_(gj));                 \
    const float hh = tanh_(cst) * sigm(go);                                    \
    if (wr) {                                                                  \
      hbuf[(p) ^ 1][u] = (_Float16)hh;                                         \
      ob[(size_t)(tt) * U_] = hh;                                              \
    }                                                                          \
    LDS_BARRIER();                                                             \
  }

#pragma unroll 1
  for (int t = 0; t < T_; t += 4) {
    STEP(t + 0, 0, gp0)
    gp0 = GXLD(t + 4);
    STEP(t + 1, 1, gp1)
    gp1 = GXLD(t + 5);
    STEP(t + 2, 0, gp2)
    gp2 = GXLD(t + 6);
    STEP(t + 3, 1, gp3)
    gp3 = GXLD(t + 7);
  }
#undef STEP
#undef LDS_BARRIER
#undef MFMA_INIT
#undef MFMA_ACC
#undef GXLD
}

// ---------------- round-1 fallback (ws too small) ---------------------------
__global__ __launch_bounds__(512, 2) void lstm_fused_kernel(
    const float* __restrict__ x, const float* __restrict__ W,
    const float* __restrict__ bias, float* __restrict__ out) {
  __shared__ __align__(16) uint32_t a_lds[2][128];
  __shared__ float g_lds[512];
  const int tid = threadIdx.x;
  const int b = blockIdx.x;
  uint32_t wreg[128];
#pragma unroll
  for (int q4 = 0; q4 < 32; ++q4) {
    float f[8];
#pragma unroll
    for (int r = 0; r < 8; ++r) f[r] = W[(q4 * 8 + r) * 512 + tid];
#pragma unroll
    for (int rr = 0; rr < 4; ++rr)
      wreg[q4 * 4 + rr] = pack2(f[2 * rr], f[2 * rr + 1]);
  }
  const float bjv = bias[tid];
  const float* xb = x + (size_t)b * (T_ * D_);
  float* ob = out + (size_t)b * (T_ * U_);
  if (tid < 32) {
    float4 x4 = reinterpret_cast<const float4*>(xb)[tid];
    reinterpret_cast<uint2*>(&a_lds[0][0])[tid] =
        make_uint2(pack2(x4.x, x4.y), pack2(x4.z, x4.w));
  }
  if (tid >= 64 && tid < 128) a_lds[0][tid] = 0u;
  __syncthreads();
  float c = 0.0f;
  int p = 0;
  for (int t = 0; t < T_; ++t) {
    float4 xp;
    const bool pf = (tid < 32) && (t + 1 < T_);
    if (pf) xp = reinterpret_cast<const float4*>(xb + (t + 1) * D_)[tid];
    const uint4* av = reinterpret_cast<const uint4*>(&a_lds[p][0]);
    float a0 = bjv, a1 = 0.0f, a2 = 0.0f, a3 = 0.0f;
#pragma unroll
    for (int q = 0; q < 32; ++q) {
      uint4 a4 = av[q];
      a0 = dot2acc(a4.x, wreg[4 * q + 0], a0);
      a1 = dot2acc(a4.y, wreg[4 * q + 1], a1);
      a2 = dot2acc(a4.z, wreg[4 * q + 2], a2);
      a3 = dot2acc(a4.w, wreg[4 * q + 3], a3);
    }
    g_lds[tid] = (a0 + a1) + (a2 + a3);
    __syncthreads();
    if (tid < 128) {
      const float gi = g_lds[tid];
      const float gj = g_lds[128 + tid];
      const float gf = g_lds[256 + tid];
      const float go = g_lds[384 + tid];
      c = c * sigm(gf + 1.0f) + sigm(gi) * tanh_(gj);
      const float h = tanh_(c) * sigm(go);
      ob[t * U_ + tid] = h;
      reinterpret_cast<_Float16*>(&a_lds[p ^ 1][64])[tid] = (_Float16)h;
    }
    if (pf) {
      reinterpret_cast<uint2*>(&a_lds[p ^ 1][0])[tid] =
          make_uint2(pack2(xp.x, xp.y), pack2(xp.z, xp.w));
    }
    __syncthreads();
    p ^= 1;
  }
}

extern "C" void kernel_launch(void* const* d_in, const int* in_sizes, int n_in,
                              void* d_out, int out_size, void* d_ws, size_t ws_size,
                              hipStream_t stream) {
  (void)in_sizes; (void)n_in; (void)out_size;
  const float* x = (const float*)d_in[0];
  const float* W = (const float*)d_in[1];
  const float* b = (const float*)d_in[2];
  float* out = (float*)d_out;

  const size_t WTX_BYTES = (size_t)512 * 128 * 2;
  const size_t WTH_BYTES = (size_t)512 * 128 * 2;
  const size_t GX_BYTES = (size_t)B_ * T_ * 512 * 2;
  if (ws_size >= WTX_BYTES + WTH_BYTES + GX_BYTES) {
    _Float16* wtx = (_Float16*)d_ws;
    _Float16* wth = (_Float16*)((char*)d_ws + WTX_BYTES);
    _Float16* gxp = (_Float16*)((char*)d_ws + WTX_BYTES + WTH_BYTES);
    wt_kernel<<<512, 256, 0, stream>>>(W, wtx, wth);
    gx_kernel<<<2048, 256, 0, stream>>>(x, wtx, b, gxp);
    rec_kernel<<<256, 512, 0, stream>>>(wth, (const uint16_t*)gxp, out);
  } else {
    lstm_fused_kernel<<<256, 512, 0, stream>>>(x, W, b, out);
  }
}